// Round 9
// baseline (85.929 us; speedup 1.0000x reference)
//
#include <hip/hip_runtime.h>

typedef unsigned int       u32;
typedef unsigned short     u16;
typedef unsigned long long u64;

// ---------------- helpers ----------------

__device__ __forceinline__ u16 f2bf(float x) {
    u32 u = __builtin_bit_cast(u32, x);
    u = (u + 0x7fffu + ((u >> 16) & 1u)) >> 16;
    return (u16)u;
}
__device__ __forceinline__ float bf_lo(u32 q) { return __builtin_bit_cast(float, q << 16); }
__device__ __forceinline__ float bf_hi(u32 q) { return __builtin_bit_cast(float, q & 0xffff0000u); }

__device__ __forceinline__ float dot8(const uint4& A, const uint4& B,
                                      const float4& w0, const float4& w1) {
    float p;
    p  = (bf_lo(A.x) * bf_lo(B.x)) * w0.x;
    p += (bf_hi(A.x) * bf_hi(B.x)) * w0.y;
    p += (bf_lo(A.y) * bf_lo(B.y)) * w0.z;
    p += (bf_hi(A.y) * bf_hi(B.y)) * w0.w;
    p += (bf_lo(A.z) * bf_lo(B.z)) * w1.x;
    p += (bf_hi(A.z) * bf_hi(B.z)) * w1.y;
    p += (bf_lo(A.w) * bf_lo(B.w)) * w1.z;
    p += (bf_hi(A.w) * bf_hi(B.w)) * w1.w;
    return p;
}

__device__ __forceinline__ float red16(float p) {
    p += __shfl_xor(p, 8);
    p += __shfl_xor(p, 4);
    p += __shfl_xor(p, 2);
    p += __shfl_xor(p, 1);
    return p;
}

__device__ __forceinline__ float sigmoidf(float x) {
    return 1.0f / (1.0f + __expf(-x));
}

// ---------------- structure ----------------
#define NSH   8      // src shards = XCDs
#define HCH   16     // hist chunk-blocks per type
#define SCH   32     // scatter chunk-blocks per type
#define CONVB 1792   // convert blocks in the fused launch

// Fused launch: blocks [0,CONVB) convert z f32->bf16 rows ([N][16] uint4);
// blocks [CONVB, CONVB+8*HCH) histogram src shards into hist[64][HCH]
// (each slot written by exactly one block -- no init needed).
__global__ __launch_bounds__(256) void convert_hist_kernel(
    const float* __restrict__ z, uint4* __restrict__ zb, int n8,
    const int* __restrict__ edge_src, int E, int shard_size,
    u32* __restrict__ hist)
{
    if ((int)blockIdx.x < CONVB) {
        int i = blockIdx.x * 256 + threadIdx.x;
        const int stride = CONVB * 256;
        const float4* __restrict__ z4 = (const float4*)z;
        for (; i < n8; i += stride) {
            float4 a = z4[2 * i];
            float4 b = z4[2 * i + 1];
            u32 p0 = (u32)f2bf(a.x) | ((u32)f2bf(a.y) << 16);
            u32 p1 = (u32)f2bf(a.z) | ((u32)f2bf(a.w) << 16);
            u32 p2 = (u32)f2bf(b.x) | ((u32)f2bf(b.y) << 16);
            u32 p3 = (u32)f2bf(b.z) | ((u32)f2bf(b.w) << 16);
            zb[i] = make_uint4(p0, p1, p2, p3);
        }
    } else {
        const int hb = (int)blockIdx.x - CONVB;   // 0..8*HCH-1
        const int t  = hb / HCH;
        const int c  = hb % HCH;
        __shared__ u32 h[4][NSH];                 // per-wave counters
        const int wv = threadIdx.x >> 6;
        if (threadIdx.x < 4 * NSH) h[threadIdx.x >> 3][threadIdx.x & 7] = 0;
        __syncthreads();
        const int chunk = (E + HCH - 1) / HCH;
        const int e0 = c * chunk;
        const int e1 = min(E, e0 + chunk);
        const int* src = edge_src + (size_t)t * E;
        for (int e = e0 + threadIdx.x; e < e1; e += 256) {
            atomicAdd(&h[wv][(u32)src[e] / (u32)shard_size], 1u);
        }
        __syncthreads();
        if (threadIdx.x < NSH) {
            u32 s = h[0][threadIdx.x] + h[1][threadIdx.x] +
                    h[2][threadIdx.x] + h[3][threadIdx.x];
            hist[(u32)(t * NSH + threadIdx.x) * HCH + c] = s;
        }
    }
}

// 64-entry scan: bstart[b] = exclusive prefix of bucket totals (bucket-major
// == type-major, so bstart[t*8] == t*E automatically). cursor = working copy.
__global__ __launch_bounds__(64) void scan64_kernel(
    const u32* __restrict__ hist, u32* __restrict__ bstart, u32* __restrict__ cursor)
{
    const int b = threadIdx.x;                    // 0..63
    u32 s = 0;
#pragma unroll
    for (int c = 0; c < HCH; c++) s += hist[b * HCH + c];
    __shared__ u32 sh[64];
    sh[b] = s;
    __syncthreads();
    for (int off = 1; off < 64; off <<= 1) {
        u32 x = (b >= off) ? sh[b - off] : 0u;
        __syncthreads();
        sh[b] += x;
        __syncthreads();
    }
    const u32 excl = (b > 0) ? sh[b - 1] : 0u;
    bstart[b] = excl;
    cursor[b] = excl;
}

// scatter: two-phase per block (count -> one global atomicAdd per bucket ->
// place). binned[p] = local_src(14b) | dst<<14 (17b) | eid<<31 (17b).
__global__ __launch_bounds__(256) void scatter_kernel(
    const int* __restrict__ edge_src, const int* __restrict__ edge_dst,
    int E, int shard_size, u32* __restrict__ cursor,
    u64* __restrict__ binned)
{
    const int t = blockIdx.x / SCH;
    const int c = blockIdx.x % SCH;
    __shared__ u32 cnt[NSH];
    __shared__ u32 pos[NSH];
    if (threadIdx.x < NSH) cnt[threadIdx.x] = 0;
    __syncthreads();
    const int chunk = (E + SCH - 1) / SCH;
    const int e0 = c * chunk;
    const int e1 = min(E, e0 + chunk);
    const int* src = edge_src + (size_t)t * E;
    const int* dst = edge_dst + (size_t)t * E;
    for (int e = e0 + threadIdx.x; e < e1; e += 256) {
        atomicAdd(&cnt[(u32)src[e] / (u32)shard_size], 1u);
    }
    __syncthreads();
    if (threadIdx.x < NSH) {
        pos[threadIdx.x] = atomicAdd(&cursor[t * NSH + threadIdx.x], cnt[threadIdx.x]);
    }
    __syncthreads();
    for (int e = e0 + threadIdx.x; e < e1; e += 256) {
        const u32 s = (u32)src[e];
        const u32 d = (u32)dst[e];
        const u32 sh_ = s / (u32)shard_size;
        const u32 local = s - sh_ * (u32)shard_size;   // < 16384
        const u32 p = atomicAdd(&pos[sh_], 1u);
        binned[p] = (u64)local | ((u64)d << 14) | ((u64)(u32)e << 31);
    }
}

// gather: bucket (t,shard) handled only by blocks with blockIdx.x&7==shard
// (round-robin wg->XCD pins the 3.2 MB src shard in one XCD's L2). dst
// gathers normal (L2-allocating); binned stream non-temporal (don't evict
// the pinned shard); results written directly to out[t*E+eid] (scattered
// 4B normal stores into a 3.2 MB hot region -- L2 write-back absorbs).
__global__ __launch_bounds__(256) void gather_binned_kernel(
    const uint4* __restrict__ zb,       // [N][16] uint4
    const float* __restrict__ weight,   // [8,128] f32
    const u64*   __restrict__ binned,
    const u32*   __restrict__ bstart,
    float*       __restrict__ out,
    int E, int shard_size)
{
    const int t      = blockIdx.y;
    const int shard  = blockIdx.x & 7;
    const int bucket = t * NSH + shard;
    const u32 start  = bstart[bucket];
    const u32 end    = (bucket == 63) ? (u32)(8 * E) : bstart[bucket + 1];
    const u32 sbase  = (u32)shard * (u32)shard_size;

    const int sub  = threadIdx.x & 15;
    const int rank = blockIdx.x >> 3;
    const int g    = rank * 16 + (threadIdx.x >> 4);
    const int ng   = (gridDim.x >> 3) * 16;

    const float4* w4 = (const float4*)(weight + (size_t)t * 128 + sub * 8);
    const float4 w0 = w4[0], w1 = w4[1];
    float* out_t = out + (size_t)t * E;

    const u32 nq = (end - start + 3) >> 2;
    for (u32 q = g; q < nq; q += ng) {
        const u32 b0 = start + q * 4;
        const bool v1 = b0 + 1 < end, v2 = b0 + 2 < end, v3 = b0 + 3 < end;
        const u64 k0 = __builtin_nontemporal_load(&binned[b0]);
        const u64 k1 = v1 ? __builtin_nontemporal_load(&binned[b0 + 1]) : k0;
        const u64 k2 = v2 ? __builtin_nontemporal_load(&binned[b0 + 2]) : k0;
        const u64 k3 = v3 ? __builtin_nontemporal_load(&binned[b0 + 3]) : k0;

        const u32 s0 = sbase + ((u32)k0 & 16383u), d0 = (u32)(k0 >> 14) & 0x1ffffu, e0 = (u32)(k0 >> 31) & 0x1ffffu;
        const u32 s1 = sbase + ((u32)k1 & 16383u), d1 = (u32)(k1 >> 14) & 0x1ffffu, e1 = (u32)(k1 >> 31) & 0x1ffffu;
        const u32 s2 = sbase + ((u32)k2 & 16383u), d2 = (u32)(k2 >> 14) & 0x1ffffu, e2 = (u32)(k2 >> 31) & 0x1ffffu;
        const u32 s3 = sbase + ((u32)k3 & 16383u), d3 = (u32)(k3 >> 14) & 0x1ffffu, e3 = (u32)(k3 >> 31) & 0x1ffffu;

        const uint4 A0 = zb[(size_t)s0 * 16 + sub];
        const uint4 A1 = zb[(size_t)s1 * 16 + sub];
        const uint4 A2 = zb[(size_t)s2 * 16 + sub];
        const uint4 A3 = zb[(size_t)s3 * 16 + sub];
        const uint4 B0 = zb[(size_t)d0 * 16 + sub];
        const uint4 B1 = zb[(size_t)d1 * 16 + sub];
        const uint4 B2 = zb[(size_t)d2 * 16 + sub];
        const uint4 B3 = zb[(size_t)d3 * 16 + sub];

        float r0 = red16(dot8(A0, B0, w0, w1));
        float r1 = red16(dot8(A1, B1, w0, w1));
        float r2 = red16(dot8(A2, B2, w0, w1));
        float r3 = red16(dot8(A3, B3, w0, w1));

        if (sub == 0) {
            out_t[e0] = sigmoidf(r0);
            if (v1) out_t[e1] = sigmoidf(r1);
            if (v2) out_t[e2] = sigmoidf(r2);
            if (v3) out_t[e3] = sigmoidf(r3);
        }
    }
}

// ---------------- fallback: round-3 path ----------------
__global__ __launch_bounds__(256) void convert_z_kernel(
    const float* __restrict__ z, uint4* __restrict__ zb, int n8)
{
    int i = blockIdx.x * blockDim.x + threadIdx.x;
    const int stride = gridDim.x * blockDim.x;
    const float4* __restrict__ z4 = (const float4*)z;
    for (; i < n8; i += stride) {
        float4 a = z4[2 * i];
        float4 b = z4[2 * i + 1];
        u32 p0 = (u32)f2bf(a.x) | ((u32)f2bf(a.y) << 16);
        u32 p1 = (u32)f2bf(a.z) | ((u32)f2bf(a.w) << 16);
        u32 p2 = (u32)f2bf(b.x) | ((u32)f2bf(b.y) << 16);
        u32 p3 = (u32)f2bf(b.z) | ((u32)f2bf(b.w) << 16);
        zb[i] = make_uint4(p0, p1, p2, p3);
    }
}

__global__ __launch_bounds__(256) void mipd_bf16_u4_kernel(
    const uint4* __restrict__ zb,
    const float* __restrict__ weight,
    const int*   __restrict__ edge_src,
    const int*   __restrict__ edge_dst,
    float*       __restrict__ out,
    int E4)
{
    const int sub     = threadIdx.x & 15;
    const int gid     = (blockIdx.x * blockDim.x + threadIdx.x) >> 4;
    const int ngroups = (gridDim.x * blockDim.x) >> 4;
    const int t       = blockIdx.y;
    const int E       = E4 * 4;

    const float4* w4 = (const float4*)(weight + (size_t)t * 128 + sub * 8);
    const float4 w0 = w4[0], w1 = w4[1];

    const int4* src4 = (const int4*)(edge_src + (size_t)t * E);
    const int4* dst4 = (const int4*)(edge_dst + (size_t)t * E);
    float4*     out4 = (float4*)(out + (size_t)t * E);

    for (int b = gid; b < E4; b += ngroups) {
        const int4 S = src4[b];
        const int4 D = dst4[b];
        const uint4 A0 = zb[(size_t)S.x * 16 + sub];
        const uint4 B0 = zb[(size_t)D.x * 16 + sub];
        const uint4 A1 = zb[(size_t)S.y * 16 + sub];
        const uint4 B1 = zb[(size_t)D.y * 16 + sub];
        const uint4 A2 = zb[(size_t)S.z * 16 + sub];
        const uint4 B2 = zb[(size_t)D.z * 16 + sub];
        const uint4 A3 = zb[(size_t)S.w * 16 + sub];
        const uint4 B3 = zb[(size_t)D.w * 16 + sub];

        float p0 = red16(dot8(A0, B0, w0, w1));
        float p1 = red16(dot8(A1, B1, w0, w1));
        float p2 = red16(dot8(A2, B2, w0, w1));
        float p3 = red16(dot8(A3, B3, w0, w1));

        if (sub == 0) {
            float4 r;
            r.x = sigmoidf(p0);
            r.y = sigmoidf(p1);
            r.z = sigmoidf(p2);
            r.w = sigmoidf(p3);
            out4[b] = r;
        }
    }
}

__global__ __launch_bounds__(256) void mipd_f32_kernel(
    const float* __restrict__ z,
    const float* __restrict__ weight,
    const int*   __restrict__ edge_src,
    const int*   __restrict__ edge_dst,
    float*       __restrict__ out,
    int E)
{
    const int lane    = threadIdx.x & 31;
    const int gid     = (blockIdx.x * blockDim.x + threadIdx.x) >> 5;
    const int ngroups = (gridDim.x * blockDim.x) >> 5;
    const int t       = blockIdx.y;

    const float4* __restrict__ z4 = (const float4*)z;
    const float4  w = ((const float4*)weight)[t * 32 + lane];

    const int* src_t = edge_src + (size_t)t * E;
    const int* dst_t = edge_dst + (size_t)t * E;
    float*     out_t = out      + (size_t)t * E;

    for (int e = gid; e < E; e += ngroups) {
        const float4 a = z4[(size_t)src_t[e] * 32 + lane];
        const float4 b = z4[(size_t)dst_t[e] * 32 + lane];
        float p = a.x * b.x * w.x + a.y * b.y * w.y
                + a.z * b.z * w.z + a.w * b.w * w.w;
        p += __shfl_xor(p, 16);
        p += __shfl_xor(p, 8);
        p += __shfl_xor(p, 4);
        p += __shfl_xor(p, 2);
        p += __shfl_xor(p, 1);
        if (lane == 0) out_t[e] = sigmoidf(p);
    }
}

// ---------------- launcher ----------------
extern "C" void kernel_launch(void* const* d_in, const int* in_sizes, int n_in,
                              void* d_out, int out_size, void* d_ws, size_t ws_size,
                              hipStream_t stream) {
    const float* z      = (const float*)d_in[0];
    const float* weight = (const float*)d_in[1];
    const int*   e_src  = (const int*)d_in[2];
    const int*   e_dst  = (const int*)d_in[3];
    float*       out    = (float*)d_out;

    const int IN_DIM = 128;
    const int T = in_sizes[1] / IN_DIM;              // 8
    const int E = in_sizes[2] / T;                   // 100000
    const int N = in_sizes[0] / IN_DIM;              // 100000
    const int shard_size = (N + 7) / 8;              // <= 16384 when N <= 131072

    const size_t zb_bytes     = (size_t)N * IN_DIM * 2;   // 25.6 MB
    const size_t binned_bytes = (size_t)T * E * 8;        // 6.4 MB
    const size_t hist_bytes   = (size_t)64 * HCH * 4;     // 4 KB
    const size_t bs_bytes     = 64 * 4;
    const size_t cur_bytes    = 64 * 4;
    const size_t fast_need    = zb_bytes + binned_bytes + hist_bytes + bs_bytes + cur_bytes;

    const bool fast = (T == 8) && (N <= 131072) && (E <= 131072) &&
                      (ws_size >= fast_need);

    if (fast) {
        char* p = (char*)d_ws;
        uint4* zb     = (uint4*)p;                 p += zb_bytes;
        u64*   binned = (u64*)p;                   p += binned_bytes;
        u32*   hist   = (u32*)p;                   p += hist_bytes;
        u32*   bstart = (u32*)p;                   p += bs_bytes;
        u32*   cursor = (u32*)p;

        hipLaunchKernelGGL(convert_hist_kernel, dim3(CONVB + 8 * HCH), dim3(256), 0, stream,
                           z, zb, N * IN_DIM / 8, e_src, E, shard_size, hist);
        hipLaunchKernelGGL(scan64_kernel, dim3(1), dim3(64), 0, stream,
                           hist, bstart, cursor);
        hipLaunchKernelGGL(scatter_kernel, dim3(8 * SCH), dim3(256), 0, stream,
                           e_src, e_dst, E, shard_size, cursor, binned);
        hipLaunchKernelGGL(gather_binned_kernel, dim3(256, 8), dim3(256), 0, stream,
                           zb, weight, binned, bstart, out, E, shard_size);
    } else if (ws_size >= zb_bytes && (E & 3) == 0) {
        uint4* zb = (uint4*)d_ws;
        hipLaunchKernelGGL(convert_z_kernel, dim3(2048), dim3(256), 0, stream,
                           z, zb, N * IN_DIM / 8);
        hipLaunchKernelGGL(mipd_bf16_u4_kernel, dim3(256, T), dim3(256), 0, stream,
                           zb, weight, e_src, e_dst, out, E >> 2);
    } else {
        hipLaunchKernelGGL(mipd_f32_kernel, dim3(512, T), dim3(256), 0, stream,
                           z, weight, e_src, e_dst, out, E);
    }
}

// Round 10
// 66.254 us; speedup vs baseline: 1.2970x; 1.2970x over previous
//
#include <hip/hip_runtime.h>

typedef unsigned int       u32;
typedef unsigned short     u16;

// ---------------- helpers ----------------

// round-to-nearest-even f32 -> bf16 bits
__device__ __forceinline__ u16 f2bf(float x) {
    u32 u = __builtin_bit_cast(u32, x);
    u = (u + 0x7fffu + ((u >> 16) & 1u)) >> 16;
    return (u16)u;
}
__device__ __forceinline__ float bf_lo(u32 q) { return __builtin_bit_cast(float, q << 16); }
__device__ __forceinline__ float bf_hi(u32 q) { return __builtin_bit_cast(float, q & 0xffff0000u); }

__device__ __forceinline__ float dot8(const uint4& A, const uint4& B,
                                      const float4& w0, const float4& w1) {
    float p;
    p  = (bf_lo(A.x) * bf_lo(B.x)) * w0.x;
    p += (bf_hi(A.x) * bf_hi(B.x)) * w0.y;
    p += (bf_lo(A.y) * bf_lo(B.y)) * w0.z;
    p += (bf_hi(A.y) * bf_hi(B.y)) * w0.w;
    p += (bf_lo(A.z) * bf_lo(B.z)) * w1.x;
    p += (bf_hi(A.z) * bf_hi(B.z)) * w1.y;
    p += (bf_lo(A.w) * bf_lo(B.w)) * w1.z;
    p += (bf_hi(A.w) * bf_hi(B.w)) * w1.w;
    return p;
}

__device__ __forceinline__ float sigmoidf(float x) {
    return 1.0f / (1.0f + __expf(-x));
}

__device__ __forceinline__ float red8(float p) {
    p += __shfl_xor(p, 4);
    p += __shfl_xor(p, 2);
    p += __shfl_xor(p, 1);
    return p;
}
__device__ __forceinline__ float red16(float p) {
    p += __shfl_xor(p, 8);
    return red8(p);
}

// ---------------- slice path (best measured config: 66.15 us) ----------------
// z split into two contiguous bf16 half-arrays (dims 0..63 / 64..127),
// 12.8 MB each; pass 0 computes partial dots over the low half, pass 1 adds
// the high half and applies sigmoid. Same logical gather bytes as single-pass
// but each pass's working set is halved and partial-store traffic overlaps
// the gather latency.

// Pass 0: z [N,128] f32 -> zbL [N][8] uint4 (dims 0..63), zbH (dims 64..127)
__global__ __launch_bounds__(256) void convert_z_split_kernel(
    const float* __restrict__ z, uint4* __restrict__ zbL, uint4* __restrict__ zbH,
    int n16)  // N*16 uint4 blocks total
{
    int i = blockIdx.x * blockDim.x + threadIdx.x;
    const int stride = gridDim.x * blockDim.x;
    const float4* __restrict__ z4 = (const float4*)z;
    for (; i < n16; i += stride) {
        float4 a = z4[2 * i];
        float4 b = z4[2 * i + 1];
        u32 p0 = (u32)f2bf(a.x) | ((u32)f2bf(a.y) << 16);
        u32 p1 = (u32)f2bf(a.z) | ((u32)f2bf(a.w) << 16);
        u32 p2 = (u32)f2bf(b.x) | ((u32)f2bf(b.y) << 16);
        u32 p3 = (u32)f2bf(b.z) | ((u32)f2bf(b.w) << 16);
        const int r = i >> 4;         // node row
        const int j = i & 15;         // uint4 index within row (0..15)
        if (j < 8) zbL[r * 8 + j]       = make_uint4(p0, p1, p2, p3);
        else       zbH[r * 8 + (j - 8)] = make_uint4(p0, p1, p2, p3);
    }
}

// Gather pass over one 64-dim half. 8 lanes per edge, 4 edges per group
// (int4 index broadcast, 8 row-gathers of 128B back-to-back).
// PASS 0: dims 0..63, writes partial sums.
// PASS 1: dims 64..127, adds partials, sigmoid, writes out.
template <int PASS>
__global__ __launch_bounds__(256) void mipd_half_kernel(
    const uint4* __restrict__ zh,       // [N][8] uint4 (one bf16 half)
    const float* __restrict__ weight,   // [T,128] f32
    const int*   __restrict__ edge_src,
    const int*   __restrict__ edge_dst,
    float*       __restrict__ part,     // [T*E] f32 partials
    float*       __restrict__ out,
    int E4)                             // E/4
{
    const int sub     = threadIdx.x & 7;
    const int gid     = (blockIdx.x * blockDim.x + threadIdx.x) >> 3;
    const int ngroups = (gridDim.x * blockDim.x) >> 3;
    const int t       = blockIdx.y;
    const int E       = E4 * 4;

    const float4* w4 = (const float4*)(weight + (size_t)t * 128 + PASS * 64 + sub * 8);
    const float4 w0 = w4[0], w1 = w4[1];

    const int4* src4 = (const int4*)(edge_src + (size_t)t * E);
    const int4* dst4 = (const int4*)(edge_dst + (size_t)t * E);
    float4*     par4 = (float4*)(part + (size_t)t * E);
    float4*     out4 = (float4*)(out + (size_t)t * E);

    for (int b = gid; b < E4; b += ngroups) {
        const int4 S = src4[b];
        const int4 D = dst4[b];

        const uint4 A0 = zh[(size_t)S.x * 8 + sub];
        const uint4 B0 = zh[(size_t)D.x * 8 + sub];
        const uint4 A1 = zh[(size_t)S.y * 8 + sub];
        const uint4 B1 = zh[(size_t)D.y * 8 + sub];
        const uint4 A2 = zh[(size_t)S.z * 8 + sub];
        const uint4 B2 = zh[(size_t)D.z * 8 + sub];
        const uint4 A3 = zh[(size_t)S.w * 8 + sub];
        const uint4 B3 = zh[(size_t)D.w * 8 + sub];

        float p0 = red8(dot8(A0, B0, w0, w1));
        float p1 = red8(dot8(A1, B1, w0, w1));
        float p2 = red8(dot8(A2, B2, w0, w1));
        float p3 = red8(dot8(A3, B3, w0, w1));

        if (sub == 0) {
            if (PASS == 0) {
                par4[b] = make_float4(p0, p1, p2, p3);
            } else {
                const float4 q = par4[b];
                float4 r;
                r.x = sigmoidf(p0 + q.x);
                r.y = sigmoidf(p1 + q.y);
                r.z = sigmoidf(p2 + q.z);
                r.w = sigmoidf(p3 + q.w);
                out4[b] = r;
            }
        }
    }
}

// ---------------- fallback path: single-pass bf16 (round-3) ----------------
__global__ __launch_bounds__(256) void convert_z_kernel(
    const float* __restrict__ z, uint4* __restrict__ zb, int n8)
{
    int i = blockIdx.x * blockDim.x + threadIdx.x;
    const int stride = gridDim.x * blockDim.x;
    const float4* __restrict__ z4 = (const float4*)z;
    for (; i < n8; i += stride) {
        float4 a = z4[2 * i];
        float4 b = z4[2 * i + 1];
        u32 p0 = (u32)f2bf(a.x) | ((u32)f2bf(a.y) << 16);
        u32 p1 = (u32)f2bf(a.z) | ((u32)f2bf(a.w) << 16);
        u32 p2 = (u32)f2bf(b.x) | ((u32)f2bf(b.y) << 16);
        u32 p3 = (u32)f2bf(b.z) | ((u32)f2bf(b.w) << 16);
        zb[i] = make_uint4(p0, p1, p2, p3);
    }
}

__global__ __launch_bounds__(256) void mipd_bf16_u4_kernel(
    const uint4* __restrict__ zb,
    const float* __restrict__ weight,
    const int*   __restrict__ edge_src,
    const int*   __restrict__ edge_dst,
    float*       __restrict__ out,
    int E4)
{
    const int sub     = threadIdx.x & 15;
    const int gid     = (blockIdx.x * blockDim.x + threadIdx.x) >> 4;
    const int ngroups = (gridDim.x * blockDim.x) >> 4;
    const int t       = blockIdx.y;
    const int E       = E4 * 4;

    const float4* w4 = (const float4*)(weight + (size_t)t * 128 + sub * 8);
    const float4 w0 = w4[0], w1 = w4[1];

    const int4* src4 = (const int4*)(edge_src + (size_t)t * E);
    const int4* dst4 = (const int4*)(edge_dst + (size_t)t * E);
    float4*     out4 = (float4*)(out + (size_t)t * E);

    for (int b = gid; b < E4; b += ngroups) {
        const int4 S = src4[b];
        const int4 D = dst4[b];
        const uint4 A0 = zb[(size_t)S.x * 16 + sub];
        const uint4 B0 = zb[(size_t)D.x * 16 + sub];
        const uint4 A1 = zb[(size_t)S.y * 16 + sub];
        const uint4 B1 = zb[(size_t)D.y * 16 + sub];
        const uint4 A2 = zb[(size_t)S.z * 16 + sub];
        const uint4 B2 = zb[(size_t)D.z * 16 + sub];
        const uint4 A3 = zb[(size_t)S.w * 16 + sub];
        const uint4 B3 = zb[(size_t)D.w * 16 + sub];

        float p0 = red16(dot8(A0, B0, w0, w1));
        float p1 = red16(dot8(A1, B1, w0, w1));
        float p2 = red16(dot8(A2, B2, w0, w1));
        float p3 = red16(dot8(A3, B3, w0, w1));

        if (sub == 0) {
            float4 r;
            r.x = sigmoidf(p0);
            r.y = sigmoidf(p1);
            r.z = sigmoidf(p2);
            r.w = sigmoidf(p3);
            out4[b] = r;
        }
    }
}

__global__ __launch_bounds__(256) void mipd_f32_kernel(
    const float* __restrict__ z,
    const float* __restrict__ weight,
    const int*   __restrict__ edge_src,
    const int*   __restrict__ edge_dst,
    float*       __restrict__ out,
    int E)
{
    const int lane    = threadIdx.x & 31;
    const int gid     = (blockIdx.x * blockDim.x + threadIdx.x) >> 5;
    const int ngroups = (gridDim.x * blockDim.x) >> 5;
    const int t       = blockIdx.y;

    const float4* __restrict__ z4 = (const float4*)z;
    const float4  w = ((const float4*)weight)[t * 32 + lane];

    const int* src_t = edge_src + (size_t)t * E;
    const int* dst_t = edge_dst + (size_t)t * E;
    float*     out_t = out      + (size_t)t * E;

    for (int e = gid; e < E; e += ngroups) {
        const float4 a = z4[(size_t)src_t[e] * 32 + lane];
        const float4 b = z4[(size_t)dst_t[e] * 32 + lane];
        float p = a.x * b.x * w.x + a.y * b.y * w.y
                + a.z * b.z * w.z + a.w * b.w * w.w;
        p += __shfl_xor(p, 16);
        p += __shfl_xor(p, 8);
        p += __shfl_xor(p, 4);
        p += __shfl_xor(p, 2);
        p += __shfl_xor(p, 1);
        if (lane == 0) out_t[e] = sigmoidf(p);
    }
}

// ---------------- launcher ----------------
extern "C" void kernel_launch(void* const* d_in, const int* in_sizes, int n_in,
                              void* d_out, int out_size, void* d_ws, size_t ws_size,
                              hipStream_t stream) {
    const float* z      = (const float*)d_in[0];
    const float* weight = (const float*)d_in[1];
    const int*   e_src  = (const int*)d_in[2];
    const int*   e_dst  = (const int*)d_in[3];
    float*       out    = (float*)d_out;

    const int IN_DIM = 128;
    const int T = in_sizes[1] / IN_DIM;              // 8
    const int E = in_sizes[2] / T;                   // 100000
    const int N = in_sizes[0] / IN_DIM;              // 100000
    const int TE = T * E;

    const size_t sl_bytes   = (size_t)N * IN_DIM * 2;  // 25.6 MB (both halves)
    const size_t part_bytes = (size_t)TE * 4;          // 3.2 MB f32 partials
    const size_t split_need = sl_bytes + part_bytes;   // 28.8 MB

    const bool split_ok = (in_sizes[0] % IN_DIM == 0) && (in_sizes[1] % IN_DIM == 0) &&
                          ((E & 3) == 0) && (ws_size >= split_need);

    if (split_ok) {
        uint4* zbL  = (uint4*)d_ws;
        uint4* zbH  = zbL + (size_t)N * 8;
        float* part = (float*)(zbH + (size_t)N * 8);
        const int n16 = N * 16;
        hipLaunchKernelGGL(convert_z_split_kernel, dim3(2048), dim3(256), 0, stream,
                           z, zbL, zbH, n16);
        hipLaunchKernelGGL((mipd_half_kernel<0>), dim3(256, T), dim3(256), 0, stream,
                           zbL, weight, e_src, e_dst, part, out, E >> 2);
        hipLaunchKernelGGL((mipd_half_kernel<1>), dim3(256, T), dim3(256), 0, stream,
                           zbH, weight, e_src, e_dst, part, out, E >> 2);
    } else if (ws_size >= sl_bytes && (E & 3) == 0) {
        uint4* zb = (uint4*)d_ws;
        hipLaunchKernelGGL(convert_z_kernel, dim3(2048), dim3(256), 0, stream,
                           z, zb, N * IN_DIM / 8);
        hipLaunchKernelGGL(mipd_bf16_u4_kernel, dim3(256, T), dim3(256), 0, stream,
                           zb, weight, e_src, e_dst, out, E >> 2);
    } else {
        hipLaunchKernelGGL(mipd_f32_kernel, dim3(512, T), dim3(256), 0, stream,
                           z, weight, e_src, e_dst, out, E);
    }
}